// Round 6
// baseline (1497.485 us; speedup 1.0000x reference)
//
#include <hip/hip_runtime.h>

#define D 128
#define NBB 392   // bucket array stride (>= nbkt+1)

typedef __attribute__((ext_vector_type(8))) short bf16x8;
typedef __attribute__((ext_vector_type(4))) float f32x4;

__device__ inline unsigned short f2bf(float f) {
  unsigned u = __builtin_bit_cast(unsigned, f);
  unsigned r = u + 0x7FFFu + ((u >> 16) & 1u);
  return (unsigned short)(r >> 16);
}
__device__ inline float bf2f(unsigned short b) {
  unsigned u = ((unsigned)b) << 16;
  return __builtin_bit_cast(float, u);
}

// ---------------- fp32 -> bf16 conversion, both tables in one launch ------
__global__ void __launch_bounds__(256) conv2_kernel(
    const float* __restrict__ xu, const float* __restrict__ xi,
    unsigned short* __restrict__ xbu, unsigned short* __restrict__ xbi,
    int n4u, int n4i) {
  int i = blockIdx.x * 256 + threadIdx.x;
  const float* x;
  unsigned short* xb;
  if (i < n4u) { x = xu; xb = xbu; }
  else { i -= n4u; if (i >= n4i) return; x = xi; xb = xbi; }
  float4 v = ((const float4*)x)[i];
  ushort4 o;
  o.x = f2bf(v.x); o.y = f2bf(v.y); o.z = f2bf(v.z); o.w = f2bf(v.w);
  ((ushort4*)xb)[i] = o;
}

// ---------------- coarse bucket histogram (bin = dst>>7) ------------------
struct Rel3 { const int* ei[3]; int ne[3]; int nb[3]; };

__global__ void __launch_bounds__(256) bhist_kernel(Rel3 R, int* __restrict__ bh) {
  int b = blockIdx.x, rel = 0;
  while (b >= R.nb[rel]) { b -= R.nb[rel]; rel++; }
  __shared__ int lh[NBB];
  for (int t = threadIdx.x; t < NBB; t += 256) lh[t] = 0;
  __syncthreads();
  const int ne = R.ne[rel];
  const int* dsts = R.ei[rel] + ne;
  const int base = b * 2048;
#pragma unroll
  for (int k = 0; k < 8; k++) {
    int i = base + k * 256 + threadIdx.x;
    if (i < ne) atomicAdd(&lh[dsts[i] >> 7], 1);
  }
  __syncthreads();
  for (int t = threadIdx.x; t < NBB; t += 256)
    if (lh[t]) atomicAdd(&bh[rel * NBB + t], lh[t]);
}

// ---------------- exclusive scan of bucket hist (3 waves, 1 block) --------
__global__ void __launch_bounds__(192) scanb_kernel(const int* __restrict__ bh,
                                                    int* __restrict__ bbase,
                                                    int* __restrict__ bcur, int nbkt) {
  int w = threadIdx.x >> 6, l = threadIdx.x & 63;
  if (w >= 3) return;
  const int off = w * NBB;
  int v[7];
  int s0 = 0;
#pragma unroll
  for (int k = 0; k < 7; k++) {
    int idx = l * 7 + k;
    v[k] = (idx < nbkt) ? bh[off + idx] : 0;
    s0 += v[k];
  }
  int s = s0;
  for (int dlt = 1; dlt < 64; dlt <<= 1) {
    int t = __shfl_up(s, dlt);
    if (l >= dlt) s += t;
  }
  int run = s - s0;
#pragma unroll
  for (int k = 0; k < 7; k++) {
    int idx = l * 7 + k;
    if (idx < nbkt) { bbase[off + idx] = run; bcur[off + idx] = run; run += v[k]; }
  }
  if (l == 63) bbase[off + nbkt] = run;
}

// ---------------- bucket partition: LDS-staged, coalesced bin runs --------
struct PArgs { const int* ei[3]; int ne[3]; int nb[3]; uint2* part[3]; };

__global__ void __launch_bounds__(256) part_kernel(PArgs P, int* __restrict__ bcur,
                                                   int nbkt) {
  int b = blockIdx.x, rel = 0;
  while (b >= P.nb[rel]) { b -= P.nb[rel]; rel++; }
  const int ne = P.ne[rel];
  const int* src = P.ei[rel];
  const int* dst = src + ne;
  const int base = b * 4096;
  const int tn = min(4096, ne - base);
  __shared__ int lh[NBB], lscan[NBB], gb[NBB], lcur[NBB];
  __shared__ uint2 pairs[4096];
  const int tid = threadIdx.x;
  for (int t = tid; t < NBB; t += 256) lh[t] = 0;
  __syncthreads();
#pragma unroll
  for (int k = 0; k < 16; k++) {
    int i = base + k * 256 + tid;
    if (i < ne) atomicAdd(&lh[dst[i] >> 7], 1);
  }
  __syncthreads();
  if (tid < 64) {
    int v[7];
    int s0 = 0;
#pragma unroll
    for (int k = 0; k < 7; k++) {
      int idx = tid * 7 + k;
      v[k] = (idx < NBB) ? lh[idx] : 0;
      s0 += v[k];
    }
    int s = s0;
    for (int dlt = 1; dlt < 64; dlt <<= 1) {
      int t = __shfl_up(s, dlt);
      if (tid >= dlt) s += t;
    }
    int run = s - s0;
#pragma unroll
    for (int k = 0; k < 7; k++) {
      int idx = tid * 7 + k;
      if (idx < NBB) { lscan[idx] = run; run += v[k]; }
    }
  }
  __syncthreads();
  for (int t = tid; t < nbkt; t += 256) {
    gb[t] = atomicAdd(&bcur[rel * NBB + t], lh[t]);
    lcur[t] = lscan[t];
  }
  __syncthreads();
#pragma unroll
  for (int k = 0; k < 16; k++) {
    int i = base + k * 256 + tid;
    if (i < ne) {
      int d = dst[i];
      int slot = atomicAdd(&lcur[d >> 7], 1);
      pairs[slot] = (uint2){(unsigned)src[i], (unsigned)d};
    }
  }
  __syncthreads();
  uint2* __restrict__ out = P.part[rel];
#pragma unroll
  for (int k = 0; k < 16; k++) {
    int slot = k * 256 + tid;
    if (slot < tn) {
      uint2 p = pairs[slot];
      int bin = (int)(p.y >> 7);
      out[gb[bin] + (slot - lscan[bin])] = p;
    }
  }
}

// ---------------- bucket aggregation: fp32 LDS acc, mean bf16 out ---------
struct AArgs {
  const uint2* part[3];
  const unsigned short* xb[3];
  unsigned short* mean[3];
  int m[3];
};

__global__ void __launch_bounds__(256) agg_kernel(AArgs A, const int* __restrict__ bbase,
                                                  int nbkt) {
  const int rel = blockIdx.x / nbkt;
  const int b = blockIdx.x - rel * nbkt;
  __shared__ float acc[128][129];   // col l = feature 2l, col 64+l = feature 2l+1
  __shared__ int cnt[128];
  const int tid = threadIdx.x;
  {
    float* af = &acc[0][0];
    for (int i = tid; i < 128 * 129; i += 256) af[i] = 0.f;
    if (tid < 128) cnt[tid] = 0;
  }
  __syncthreads();
  const int bs = bbase[rel * NBB + b];
  const int be = bbase[rel * NBB + b + 1];
  const uint2* __restrict__ pp = A.part[rel];
  const unsigned short* __restrict__ x = A.xb[rel];
  const int w = tid >> 6, l = tid & 63;
  const int loff = 2 * l;
  int j = bs + (w << 2);
  for (; j + 4 <= be; j += 16) {
    uint2 p0 = pp[j], p1 = pp[j + 1], p2 = pp[j + 2], p3 = pp[j + 3];
    unsigned u0 = *(const unsigned*)(x + (size_t)p0.x * D + loff);
    unsigned u1 = *(const unsigned*)(x + (size_t)p1.x * D + loff);
    unsigned u2 = *(const unsigned*)(x + (size_t)p2.x * D + loff);
    unsigned u3 = *(const unsigned*)(x + (size_t)p3.x * D + loff);
    int d0 = p0.y & 127, d1 = p1.y & 127, d2 = p2.y & 127, d3 = p3.y & 127;
    unsafeAtomicAdd(&acc[d0][l],      bf2f((unsigned short)(u0 & 0xFFFFu)));
    unsafeAtomicAdd(&acc[d0][64 + l], bf2f((unsigned short)(u0 >> 16)));
    unsafeAtomicAdd(&acc[d1][l],      bf2f((unsigned short)(u1 & 0xFFFFu)));
    unsafeAtomicAdd(&acc[d1][64 + l], bf2f((unsigned short)(u1 >> 16)));
    unsafeAtomicAdd(&acc[d2][l],      bf2f((unsigned short)(u2 & 0xFFFFu)));
    unsafeAtomicAdd(&acc[d2][64 + l], bf2f((unsigned short)(u2 >> 16)));
    unsafeAtomicAdd(&acc[d3][l],      bf2f((unsigned short)(u3 & 0xFFFFu)));
    unsafeAtomicAdd(&acc[d3][64 + l], bf2f((unsigned short)(u3 >> 16)));
    if (l == 0) {
      atomicAdd(&cnt[d0], 1); atomicAdd(&cnt[d1], 1);
      atomicAdd(&cnt[d2], 1); atomicAdd(&cnt[d3], 1);
    }
  }
  for (; j < be; j++) {
    uint2 p = pp[j];
    unsigned u = *(const unsigned*)(x + (size_t)p.x * D + loff);
    int dd = p.y & 127;
    unsafeAtomicAdd(&acc[dd][l],      bf2f((unsigned short)(u & 0xFFFFu)));
    unsafeAtomicAdd(&acc[dd][64 + l], bf2f((unsigned short)(u >> 16)));
    if (l == 0) atomicAdd(&cnt[dd], 1);
  }
  __syncthreads();
  const int r = tid >> 1, half = tid & 1;
  const int gdst = b * 128 + r;
  if (gdst < A.m[rel]) {
    float inv = 1.0f / (float)max(cnt[r], 1);
    unsigned* orow = (unsigned*)(A.mean[rel] + (size_t)gdst * D) + half * 32;
#pragma unroll
    for (int i0 = 0; i0 < 32; i0 += 4) {
      const int c = half * 32 + i0;
      uint4 o;
      o.x = (unsigned)f2bf(acc[r][c + 0] * inv) | ((unsigned)f2bf(acc[r][64 + c + 0] * inv) << 16);
      o.y = (unsigned)f2bf(acc[r][c + 1] * inv) | ((unsigned)f2bf(acc[r][64 + c + 1] * inv) << 16);
      o.z = (unsigned)f2bf(acc[r][c + 2] * inv) | ((unsigned)f2bf(acc[r][64 + c + 2] * inv) << 16);
      o.w = (unsigned)f2bf(acc[r][c + 3] * inv) | ((unsigned)f2bf(acc[r][64 + c + 3] * inv) << 16);
      *(uint4*)(orow + i0) = o;
    }
  }
}

// ---------------- prep: combined bf16 weights (n-major) + biases ----------
__global__ void __launch_bounds__(384) prep_kernel(
    const float* __restrict__ Wl_rates, const float* __restrict__ Wr_rates, const float* __restrict__ bl_rates,
    const float* __restrict__ Wl_rev, const float* __restrict__ Wr_rev, const float* __restrict__ bl_rev,
    const float* __restrict__ Wl_fol, const float* __restrict__ Wr_fol, const float* __restrict__ bl_fol,
    unsigned short* __restrict__ Wb_user, unsigned short* __restrict__ Wb_item,
    float* __restrict__ b_user, float* __restrict__ b_item) {
  int n = blockIdx.x;          // 0..127
  int k = threadIdx.x;         // 0..383
  float v;
  if (k < 128)      v = 0.5f * Wl_rev[n * 128 + k];
  else if (k < 256) v = 0.5f * Wl_fol[n * 128 + (k - 128)];
  else              v = 0.5f * (Wr_rev[n * 128 + (k - 256)] + Wr_fol[n * 128 + (k - 256)]);
  Wb_user[n * 384 + k] = f2bf(v);
  if (k < 256) {
    float w = (k < 128) ? Wl_rates[n * 128 + k] : Wr_rates[n * 128 + (k - 128)];
    Wb_item[n * 256 + k] = f2bf(w);
  }
  if (n == 0 && k < 128) {
    b_item[k] = bl_rates[k];
    b_user[k] = 0.5f * (bl_rev[k] + bl_fol[k]);
  }
}

// ---------------- bf16 MFMA GEMM, both outputs in one launch --------------
struct BSrcs { const unsigned short* s[3]; };
struct GemmArgs {
  BSrcs su, si;
  const unsigned short* wbU; const unsigned short* wbI;
  const float* bU; const float* bI;
  float* outU; float* outI;
  int MU, MI, nbU;
};

__global__ void __launch_bounds__(256) gemm2_kernel(GemmArgs A) {
  const bool isU = (int)blockIdx.x < A.nbU;
  const int bid = isU ? blockIdx.x : blockIdx.x - A.nbU;
  const BSrcs S = isU ? A.su : A.si;
  const unsigned short* __restrict__ Wb = isU ? A.wbU : A.wbI;
  const int K = isU ? 384 : 256;
  const float* __restrict__ bias = isU ? A.bU : A.bI;
  float* __restrict__ out = isU ? A.outU : A.outI;
  const int M = isU ? A.MU : A.MI;

  __shared__ __align__(16) unsigned short As[64][72];
  __shared__ __align__(16) unsigned short Ws[128][72];
  const int tid = threadIdx.x;
  const int lane = tid & 63;
  const int wave = tid >> 6;
  const int wrow = (wave >> 1) * 32;
  const int wcol = (wave & 1) * 64;
  const int l15 = lane & 15;
  const int quad = lane >> 4;
  const int m0 = bid * 64;

  f32x4 acc[2][4];
#pragma unroll
  for (int r = 0; r < 2; r++)
#pragma unroll
    for (int c = 0; c < 4; c++) acc[r][c] = (f32x4){0.f, 0.f, 0.f, 0.f};

  const int nchunks = K >> 6;
  for (int ch = 0; ch < nchunks; ch++) {
    const unsigned short* sp = S.s[ch >> 1];
    const int coff = (ch & 1) << 6;
    {
      int row = tid >> 2, part = tid & 3;
      int m = m0 + row;
      uint4 v0 = {0, 0, 0, 0}, v1 = {0, 0, 0, 0};
      if (m < M) {
        const uint4* g = (const uint4*)(sp + (size_t)m * D + coff + part * 16);
        v0 = g[0]; v1 = g[1];
      }
      uint4* ld = (uint4*)(&As[row][part * 16]);
      ld[0] = v0; ld[1] = v1;
    }
    {
      int n = tid >> 1, half = tid & 1;
      const uint4* g = (const uint4*)(Wb + (size_t)n * K + ch * 64 + half * 32);
      uint4* ld = (uint4*)(&Ws[n][half * 32]);
      ld[0] = g[0]; ld[1] = g[1]; ld[2] = g[2]; ld[3] = g[3];
    }
    __syncthreads();
#pragma unroll
    for (int kk = 0; kk < 64; kk += 32) {
      const int kb = kk + quad * 8;
      bf16x8 a0 = *(const bf16x8*)&As[wrow + l15][kb];
      bf16x8 a1 = *(const bf16x8*)&As[wrow + 16 + l15][kb];
      bf16x8 b0 = *(const bf16x8*)&Ws[wcol + l15][kb];
      bf16x8 b1 = *(const bf16x8*)&Ws[wcol + 16 + l15][kb];
      bf16x8 b2 = *(const bf16x8*)&Ws[wcol + 32 + l15][kb];
      bf16x8 b3 = *(const bf16x8*)&Ws[wcol + 48 + l15][kb];
      acc[0][0] = __builtin_amdgcn_mfma_f32_16x16x32_bf16(a0, b0, acc[0][0], 0, 0, 0);
      acc[0][1] = __builtin_amdgcn_mfma_f32_16x16x32_bf16(a0, b1, acc[0][1], 0, 0, 0);
      acc[0][2] = __builtin_amdgcn_mfma_f32_16x16x32_bf16(a0, b2, acc[0][2], 0, 0, 0);
      acc[0][3] = __builtin_amdgcn_mfma_f32_16x16x32_bf16(a0, b3, acc[0][3], 0, 0, 0);
      acc[1][0] = __builtin_amdgcn_mfma_f32_16x16x32_bf16(a1, b0, acc[1][0], 0, 0, 0);
      acc[1][1] = __builtin_amdgcn_mfma_f32_16x16x32_bf16(a1, b1, acc[1][1], 0, 0, 0);
      acc[1][2] = __builtin_amdgcn_mfma_f32_16x16x32_bf16(a1, b2, acc[1][2], 0, 0, 0);
      acc[1][3] = __builtin_amdgcn_mfma_f32_16x16x32_bf16(a1, b3, acc[1][3], 0, 0, 0);
    }
    __syncthreads();
  }
#pragma unroll
  for (int c = 0; c < 4; c++) {
    const int n = wcol + c * 16 + l15;
    const float bv = bias[n];
#pragma unroll
    for (int r = 0; r < 2; r++) {
      const int mrow = m0 + wrow + r * 16 + quad * 4;
#pragma unroll
      for (int i = 0; i < 4; i++) {
        if (mrow + i < M) out[(size_t)(mrow + i) * D + n] = acc[r][c][i] + bv;
      }
    }
  }
}

extern "C" void kernel_launch(void* const* d_in, const int* in_sizes, int n_in,
                              void* d_out, int out_size, void* d_ws, size_t ws_size,
                              hipStream_t stream) {
  const float* x_user   = (const float*)d_in[0];
  const float* x_item   = (const float*)d_in[1];
  const int*   ei_rates = (const int*)d_in[2];
  const int*   ei_rev   = (const int*)d_in[3];
  const int*   ei_fol   = (const int*)d_in[4];
  const float* Wl_rates = (const float*)d_in[5];
  const float* bl_rates = (const float*)d_in[6];
  const float* Wr_rates = (const float*)d_in[7];
  const float* Wl_rev   = (const float*)d_in[8];
  const float* bl_rev   = (const float*)d_in[9];
  const float* Wr_rev   = (const float*)d_in[10];
  const float* Wl_fol   = (const float*)d_in[11];
  const float* bl_fol   = (const float*)d_in[12];
  const float* Wr_fol   = (const float*)d_in[13];

  const int NU = in_sizes[0] / D;       // 50000
  const int NI = in_sizes[1] / D;       // 50000
  const int E_rates = in_sizes[2] / 2;
  const int E_rev   = in_sizes[3] / 2;
  const int E_fol   = in_sizes[4] / 2;
  const int nbkt = ((NU > NI ? NU : NI) + 127) / 128;   // 391

  // ---- workspace carve-up (byte-based, 16B aligned) ----
  char* wsb = (char*)d_ws;
  size_t off = 0;
  auto take = [&](size_t bytes) {
    char* p = wsb + off;
    off += (bytes + 15) & ~(size_t)15;
    return p;
  };
  int* bhist = (int*)take(3 * NBB * 4);          // zeroed
  const size_t zero_bytes = off;
  int* bbase = (int*)take(3 * NBB * 4);
  int* bcur  = (int*)take(3 * NBB * 4);
  uint2* part_rates = (uint2*)take((size_t)E_rates * 8);
  uint2* part_rev   = (uint2*)take((size_t)E_rev * 8);
  uint2* part_fol   = (uint2*)take((size_t)E_fol * 8);
  unsigned short* xb_user    = (unsigned short*)take((size_t)NU * D * 2);
  unsigned short* xb_item    = (unsigned short*)take((size_t)NI * D * 2);
  unsigned short* mean_rates = (unsigned short*)take((size_t)NI * D * 2);
  unsigned short* mean_rev   = (unsigned short*)take((size_t)NU * D * 2);
  unsigned short* mean_fol   = (unsigned short*)take((size_t)NU * D * 2);
  unsigned short* Wb_user    = (unsigned short*)take(128 * 384 * 2);
  unsigned short* Wb_item    = (unsigned short*)take(128 * 256 * 2);
  float* b_user = (float*)take(128 * 4);
  float* b_item = (float*)take(128 * 4);

  hipMemsetAsync(d_ws, 0, zero_bytes, stream);
  prep_kernel<<<128, 384, 0, stream>>>(Wl_rates, Wr_rates, bl_rates,
                                       Wl_rev, Wr_rev, bl_rev,
                                       Wl_fol, Wr_fol, bl_fol,
                                       Wb_user, Wb_item, b_user, b_item);
  {
    int n4u = NU * D / 4, n4i = NI * D / 4;
    conv2_kernel<<<(n4u + n4i + 255) / 256, 256, 0, stream>>>(
        x_user, x_item, xb_user, xb_item, n4u, n4i);
  }

  Rel3 R;
  R.ei[0] = ei_rates; R.ne[0] = E_rates; R.nb[0] = (E_rates + 2047) / 2048;
  R.ei[1] = ei_rev;   R.ne[1] = E_rev;   R.nb[1] = (E_rev + 2047) / 2048;
  R.ei[2] = ei_fol;   R.ne[2] = E_fol;   R.nb[2] = (E_fol + 2047) / 2048;
  bhist_kernel<<<R.nb[0] + R.nb[1] + R.nb[2], 256, 0, stream>>>(R, bhist);

  scanb_kernel<<<1, 192, 0, stream>>>(bhist, bbase, bcur, nbkt);

  PArgs P;
  P.ei[0] = ei_rates; P.ne[0] = E_rates; P.nb[0] = (E_rates + 4095) / 4096; P.part[0] = part_rates;
  P.ei[1] = ei_rev;   P.ne[1] = E_rev;   P.nb[1] = (E_rev + 4095) / 4096;   P.part[1] = part_rev;
  P.ei[2] = ei_fol;   P.ne[2] = E_fol;   P.nb[2] = (E_fol + 4095) / 4096;   P.part[2] = part_fol;
  part_kernel<<<P.nb[0] + P.nb[1] + P.nb[2], 256, 0, stream>>>(P, bcur, nbkt);

  AArgs A;
  A.part[0] = part_rates; A.xb[0] = xb_user; A.mean[0] = mean_rates; A.m[0] = NI;
  A.part[1] = part_rev;   A.xb[1] = xb_item; A.mean[1] = mean_rev;   A.m[1] = NU;
  A.part[2] = part_fol;   A.xb[2] = xb_user; A.mean[2] = mean_fol;   A.m[2] = NU;
  agg_kernel<<<3 * nbkt, 256, 0, stream>>>(A, bbase, nbkt);

  GemmArgs gma;
  gma.su.s[0] = mean_rev;   gma.su.s[1] = mean_fol; gma.su.s[2] = xb_user;
  gma.si.s[0] = mean_rates; gma.si.s[1] = xb_item;  gma.si.s[2] = nullptr;
  gma.wbU = Wb_user; gma.wbI = Wb_item;
  gma.bU = b_user;   gma.bI = b_item;
  gma.outU = (float*)d_out;
  gma.outI = (float*)d_out + (size_t)NU * D;
  gma.MU = NU; gma.MI = NI;
  gma.nbU = (NU + 63) / 64;
  const int nbI = (NI + 63) / 64;
  gemm2_kernel<<<gma.nbU + nbI, 256, 0, stream>>>(gma);
}

// Round 7
// 313.722 us; speedup vs baseline: 4.7733x; 4.7733x over previous
//
#include <hip/hip_runtime.h>

#define D 128
#define NBB 392   // bucket array stride (>= nbkt+1)

typedef __attribute__((ext_vector_type(8))) short bf16x8;
typedef __attribute__((ext_vector_type(4))) float f32x4;

__device__ inline unsigned short f2bf(float f) {
  unsigned u = __builtin_bit_cast(unsigned, f);
  unsigned r = u + 0x7FFFu + ((u >> 16) & 1u);
  return (unsigned short)(r >> 16);
}
__device__ inline float bf2f(unsigned short b) {
  unsigned u = ((unsigned)b) << 16;
  return __builtin_bit_cast(float, u);
}

// ---------------- fp32 -> bf16 conversion, both tables in one launch ------
__global__ void __launch_bounds__(256) conv2_kernel(
    const float* __restrict__ xu, const float* __restrict__ xi,
    unsigned short* __restrict__ xbu, unsigned short* __restrict__ xbi,
    int n4u, int n4i) {
  int i = blockIdx.x * 256 + threadIdx.x;
  const float* x;
  unsigned short* xb;
  if (i < n4u) { x = xu; xb = xbu; }
  else { i -= n4u; if (i >= n4i) return; x = xi; xb = xbi; }
  float4 v = ((const float4*)x)[i];
  ushort4 o;
  o.x = f2bf(v.x); o.y = f2bf(v.y); o.z = f2bf(v.z); o.w = f2bf(v.w);
  ((ushort4*)xb)[i] = o;
}

// ---------------- coarse bucket histogram (bin = dst>>7) ------------------
struct Rel3 { const int* ei[3]; int ne[3]; int nb[3]; };

__global__ void __launch_bounds__(256) bhist_kernel(Rel3 R, int* __restrict__ bh) {
  int b = blockIdx.x, rel = 0;
  while (b >= R.nb[rel]) { b -= R.nb[rel]; rel++; }
  __shared__ int lh[NBB];
  for (int t = threadIdx.x; t < NBB; t += 256) lh[t] = 0;
  __syncthreads();
  const int ne = R.ne[rel];
  const int* dsts = R.ei[rel] + ne;
  const int base = b * 2048;
#pragma unroll
  for (int k = 0; k < 8; k++) {
    int i = base + k * 256 + threadIdx.x;
    if (i < ne) atomicAdd(&lh[dsts[i] >> 7], 1);
  }
  __syncthreads();
  for (int t = threadIdx.x; t < NBB; t += 256)
    if (lh[t]) atomicAdd(&bh[rel * NBB + t], lh[t]);
}

// ---------------- exclusive scan of bucket hist (3 waves, 1 block) --------
__global__ void __launch_bounds__(192) scanb_kernel(const int* __restrict__ bh,
                                                    int* __restrict__ bbase,
                                                    int* __restrict__ bcur, int nbkt) {
  int w = threadIdx.x >> 6, l = threadIdx.x & 63;
  if (w >= 3) return;
  const int off = w * NBB;
  int v[7];
  int s0 = 0;
#pragma unroll
  for (int k = 0; k < 7; k++) {
    int idx = l * 7 + k;
    v[k] = (idx < nbkt) ? bh[off + idx] : 0;
    s0 += v[k];
  }
  int s = s0;
  for (int dlt = 1; dlt < 64; dlt <<= 1) {
    int t = __shfl_up(s, dlt);
    if (l >= dlt) s += t;
  }
  int run = s - s0;
#pragma unroll
  for (int k = 0; k < 7; k++) {
    int idx = l * 7 + k;
    if (idx < nbkt) { bbase[off + idx] = run; bcur[off + idx] = run; run += v[k]; }
  }
  if (l == 63) bbase[off + nbkt] = run;
}

// --------- bucket partition: packed (src | (dst&127)<<25), coalesced ------
struct PArgs { const int* ei[3]; int ne[3]; int nb[3]; unsigned* part[3]; };

__global__ void __launch_bounds__(256) part_kernel(PArgs P, int* __restrict__ bcur,
                                                   int nbkt) {
  int b = blockIdx.x, rel = 0;
  while (b >= P.nb[rel]) { b -= P.nb[rel]; rel++; }
  const int ne = P.ne[rel];
  const int* src = P.ei[rel];
  const int* dst = src + ne;
  const int base = b * 4096;
  const int tn = min(4096, ne - base);
  __shared__ int lh[NBB], lscan[NBB], gb[NBB], lcur[NBB];
  __shared__ uint2 pairs[4096];
  const int tid = threadIdx.x;
  for (int t = tid; t < NBB; t += 256) lh[t] = 0;
  __syncthreads();
#pragma unroll
  for (int k = 0; k < 16; k++) {
    int i = base + k * 256 + tid;
    if (i < ne) atomicAdd(&lh[dst[i] >> 7], 1);
  }
  __syncthreads();
  if (tid < 64) {
    int v[7];
    int s0 = 0;
#pragma unroll
    for (int k = 0; k < 7; k++) {
      int idx = tid * 7 + k;
      v[k] = (idx < NBB) ? lh[idx] : 0;
      s0 += v[k];
    }
    int s = s0;
    for (int dlt = 1; dlt < 64; dlt <<= 1) {
      int t = __shfl_up(s, dlt);
      if (tid >= dlt) s += t;
    }
    int run = s - s0;
#pragma unroll
    for (int k = 0; k < 7; k++) {
      int idx = tid * 7 + k;
      if (idx < NBB) { lscan[idx] = run; run += v[k]; }
    }
  }
  __syncthreads();
  for (int t = tid; t < nbkt; t += 256) {
    gb[t] = atomicAdd(&bcur[rel * NBB + t], lh[t]);
    lcur[t] = lscan[t];
  }
  __syncthreads();
#pragma unroll
  for (int k = 0; k < 16; k++) {
    int i = base + k * 256 + tid;
    if (i < ne) {
      int d = dst[i];
      int slot = atomicAdd(&lcur[d >> 7], 1);
      pairs[slot] = (uint2){(unsigned)src[i], (unsigned)d};
    }
  }
  __syncthreads();
  unsigned* __restrict__ out = P.part[rel];
#pragma unroll
  for (int k = 0; k < 16; k++) {
    int slot = k * 256 + tid;
    if (slot < tn) {
      uint2 p = pairs[slot];
      int bin = (int)(p.y >> 7);
      out[gb[bin] + (slot - lscan[bin])] = p.x | ((p.y & 127u) << 25);
    }
  }
}

// ------ per-bucket counting sort -> rowptr + dst-sorted src list ----------
struct S2Args {
  const unsigned* part[3];
  int* rp[3];
  int* es[3];
  int m[3];
};

__global__ void __launch_bounds__(256) sort2_kernel(S2Args A, const int* __restrict__ bbase,
                                                    int nbkt) {
  const int rel = blockIdx.x / nbkt;
  const int b = blockIdx.x - rel * nbkt;
  const int bs = bbase[rel * NBB + b];
  const int be = bbase[rel * NBB + b + 1];
  const int n = be - bs;
  const unsigned* __restrict__ pp = A.part[rel] + bs;
  int* __restrict__ es = A.es[rel];
  const int tid = threadIdx.x;
  __shared__ unsigned stage[4096];
  __shared__ int lcnt[128], lofs[128], lcur[128];
  if (tid < 128) lcnt[tid] = 0;
  __syncthreads();
  const bool staged = (n <= 4096);
  if (staged) {
    for (int i = tid; i < n; i += 256) {
      unsigned p = pp[i];
      stage[i] = p;
      atomicAdd(&lcnt[p >> 25], 1);
    }
  } else {
    for (int i = tid; i < n; i += 256) atomicAdd(&lcnt[pp[i] >> 25], 1);
  }
  __syncthreads();
  if (tid < 64) {
    int v0 = lcnt[2 * tid], v1 = lcnt[2 * tid + 1];
    int s0 = v0 + v1;
    int s = s0;
    for (int dlt = 1; dlt < 64; dlt <<= 1) {
      int t = __shfl_up(s, dlt);
      if (tid >= dlt) s += t;
    }
    int ex = s - s0;
    lofs[2 * tid] = ex;
    lofs[2 * tid + 1] = ex + v0;
  }
  __syncthreads();
  if (tid < 128) {
    int gdst = b * 128 + tid;
    if (gdst < A.m[rel]) A.rp[rel][gdst] = bs + lofs[tid];
    lcur[tid] = lofs[tid];
  }
  if (b == nbkt - 1 && tid == 0) A.rp[rel][A.m[rel]] = bbase[rel * NBB + nbkt];
  __syncthreads();
  if (staged) {
    for (int i = tid; i < n; i += 256) {
      unsigned p = stage[i];
      int slot = atomicAdd(&lcur[p >> 25], 1);
      es[bs + slot] = (int)(p & 0x1FFFFFFu);
    }
  } else {
    for (int i = tid; i < n; i += 256) {
      unsigned p = pp[i];
      int slot = atomicAdd(&lcur[p >> 25], 1);
      es[bs + slot] = (int)(p & 0x1FFFFFFu);
    }
  }
}

// ------- gather + mean, 3 relations, one wave/row, 4-way unrolled ---------
struct GatherArgs {
  const unsigned short* xb[3];
  const int* rp[3];
  const int* es[3];
  unsigned short* mean[3];
  int m[3];
  int nb[3];
};

__global__ void __launch_bounds__(256) gather3_kernel(GatherArgs G) {
  int b = blockIdx.x, rel = 0;
  while (b >= G.nb[rel]) { b -= G.nb[rel]; rel++; }
  int row = b * 4 + (threadIdx.x >> 6);
  if (row >= G.m[rel]) return;
  const int lane = threadIdx.x & 63;
  const unsigned short* __restrict__ xb = G.xb[rel];
  const int* __restrict__ rowptr = G.rp[rel];
  const int* __restrict__ esrc = G.es[rel];
  const int beg = rowptr[row], end = rowptr[row + 1];
  const size_t loff = lane * 2;
  float a0 = 0.f, a1 = 0.f, b0 = 0.f, b1 = 0.f;
  float c0 = 0.f, c1 = 0.f, d0 = 0.f, d1 = 0.f;
  int j = beg;
  for (; j + 4 <= end; j += 4) {
    int s0 = esrc[j], s1 = esrc[j + 1], s2 = esrc[j + 2], s3 = esrc[j + 3];
    unsigned v0 = *(const unsigned*)(xb + (size_t)s0 * D + loff);
    unsigned v1 = *(const unsigned*)(xb + (size_t)s1 * D + loff);
    unsigned v2 = *(const unsigned*)(xb + (size_t)s2 * D + loff);
    unsigned v3 = *(const unsigned*)(xb + (size_t)s3 * D + loff);
    a0 += bf2f((unsigned short)(v0 & 0xFFFFu)); a1 += bf2f((unsigned short)(v0 >> 16));
    b0 += bf2f((unsigned short)(v1 & 0xFFFFu)); b1 += bf2f((unsigned short)(v1 >> 16));
    c0 += bf2f((unsigned short)(v2 & 0xFFFFu)); c1 += bf2f((unsigned short)(v2 >> 16));
    d0 += bf2f((unsigned short)(v3 & 0xFFFFu)); d1 += bf2f((unsigned short)(v3 >> 16));
  }
  for (; j < end; j++) {
    int s = esrc[j];
    unsigned v = *(const unsigned*)(xb + (size_t)s * D + loff);
    a0 += bf2f((unsigned short)(v & 0xFFFFu)); a1 += bf2f((unsigned short)(v >> 16));
  }
  a0 += (b0 + c0) + d0;
  a1 += (b1 + c1) + d1;
  float inv = 1.0f / (float)max(end - beg, 1);
  unsigned o = (unsigned)f2bf(a0 * inv) | ((unsigned)f2bf(a1 * inv) << 16);
  *(unsigned*)(G.mean[rel] + (size_t)row * D + loff) = o;
}

// ---------------- prep: combined bf16 weights (n-major) + biases ----------
__global__ void __launch_bounds__(384) prep_kernel(
    const float* __restrict__ Wl_rates, const float* __restrict__ Wr_rates, const float* __restrict__ bl_rates,
    const float* __restrict__ Wl_rev, const float* __restrict__ Wr_rev, const float* __restrict__ bl_rev,
    const float* __restrict__ Wl_fol, const float* __restrict__ Wr_fol, const float* __restrict__ bl_fol,
    unsigned short* __restrict__ Wb_user, unsigned short* __restrict__ Wb_item,
    float* __restrict__ b_user, float* __restrict__ b_item) {
  int n = blockIdx.x;          // 0..127
  int k = threadIdx.x;         // 0..383
  float v;
  if (k < 128)      v = 0.5f * Wl_rev[n * 128 + k];
  else if (k < 256) v = 0.5f * Wl_fol[n * 128 + (k - 128)];
  else              v = 0.5f * (Wr_rev[n * 128 + (k - 256)] + Wr_fol[n * 128 + (k - 256)]);
  Wb_user[n * 384 + k] = f2bf(v);
  if (k < 256) {
    float w = (k < 128) ? Wl_rates[n * 128 + k] : Wr_rates[n * 128 + (k - 128)];
    Wb_item[n * 256 + k] = f2bf(w);
  }
  if (n == 0 && k < 128) {
    b_item[k] = bl_rates[k];
    b_user[k] = 0.5f * (bl_rev[k] + bl_fol[k]);
  }
}

// ---------------- bf16 MFMA GEMM, both outputs in one launch --------------
struct BSrcs { const unsigned short* s[3]; };
struct GemmArgs {
  BSrcs su, si;
  const unsigned short* wbU; const unsigned short* wbI;
  const float* bU; const float* bI;
  float* outU; float* outI;
  int MU, MI, nbU;
};

__global__ void __launch_bounds__(256) gemm2_kernel(GemmArgs A) {
  const bool isU = (int)blockIdx.x < A.nbU;
  const int bid = isU ? blockIdx.x : blockIdx.x - A.nbU;
  const BSrcs S = isU ? A.su : A.si;
  const unsigned short* __restrict__ Wb = isU ? A.wbU : A.wbI;
  const int K = isU ? 384 : 256;
  const float* __restrict__ bias = isU ? A.bU : A.bI;
  float* __restrict__ out = isU ? A.outU : A.outI;
  const int M = isU ? A.MU : A.MI;

  __shared__ __align__(16) unsigned short As[64][72];
  __shared__ __align__(16) unsigned short Ws[128][72];
  const int tid = threadIdx.x;
  const int lane = tid & 63;
  const int wave = tid >> 6;
  const int wrow = (wave >> 1) * 32;
  const int wcol = (wave & 1) * 64;
  const int l15 = lane & 15;
  const int quad = lane >> 4;
  const int m0 = bid * 64;

  f32x4 acc[2][4];
#pragma unroll
  for (int r = 0; r < 2; r++)
#pragma unroll
    for (int c = 0; c < 4; c++) acc[r][c] = (f32x4){0.f, 0.f, 0.f, 0.f};

  const int nchunks = K >> 6;
  for (int ch = 0; ch < nchunks; ch++) {
    const unsigned short* sp = S.s[ch >> 1];
    const int coff = (ch & 1) << 6;
    {
      int row = tid >> 2, part = tid & 3;
      int m = m0 + row;
      uint4 v0 = {0, 0, 0, 0}, v1 = {0, 0, 0, 0};
      if (m < M) {
        const uint4* g = (const uint4*)(sp + (size_t)m * D + coff + part * 16);
        v0 = g[0]; v1 = g[1];
      }
      uint4* ld = (uint4*)(&As[row][part * 16]);
      ld[0] = v0; ld[1] = v1;
    }
    {
      int n = tid >> 1, half = tid & 1;
      const uint4* g = (const uint4*)(Wb + (size_t)n * K + ch * 64 + half * 32);
      uint4* ld = (uint4*)(&Ws[n][half * 32]);
      ld[0] = g[0]; ld[1] = g[1]; ld[2] = g[2]; ld[3] = g[3];
    }
    __syncthreads();
#pragma unroll
    for (int kk = 0; kk < 64; kk += 32) {
      const int kb = kk + quad * 8;
      bf16x8 a0 = *(const bf16x8*)&As[wrow + l15][kb];
      bf16x8 a1 = *(const bf16x8*)&As[wrow + 16 + l15][kb];
      bf16x8 b0 = *(const bf16x8*)&Ws[wcol + l15][kb];
      bf16x8 b1 = *(const bf16x8*)&Ws[wcol + 16 + l15][kb];
      bf16x8 b2 = *(const bf16x8*)&Ws[wcol + 32 + l15][kb];
      bf16x8 b3 = *(const bf16x8*)&Ws[wcol + 48 + l15][kb];
      acc[0][0] = __builtin_amdgcn_mfma_f32_16x16x32_bf16(a0, b0, acc[0][0], 0, 0, 0);
      acc[0][1] = __builtin_amdgcn_mfma_f32_16x16x32_bf16(a0, b1, acc[0][1], 0, 0, 0);
      acc[0][2] = __builtin_amdgcn_mfma_f32_16x16x32_bf16(a0, b2, acc[0][2], 0, 0, 0);
      acc[0][3] = __builtin_amdgcn_mfma_f32_16x16x32_bf16(a0, b3, acc[0][3], 0, 0, 0);
      acc[1][0] = __builtin_amdgcn_mfma_f32_16x16x32_bf16(a1, b0, acc[1][0], 0, 0, 0);
      acc[1][1] = __builtin_amdgcn_mfma_f32_16x16x32_bf16(a1, b1, acc[1][1], 0, 0, 0);
      acc[1][2] = __builtin_amdgcn_mfma_f32_16x16x32_bf16(a1, b2, acc[1][2], 0, 0, 0);
      acc[1][3] = __builtin_amdgcn_mfma_f32_16x16x32_bf16(a1, b3, acc[1][3], 0, 0, 0);
    }
    __syncthreads();
  }
#pragma unroll
  for (int c = 0; c < 4; c++) {
    const int n = wcol + c * 16 + l15;
    const float bv = bias[n];
#pragma unroll
    for (int r = 0; r < 2; r++) {
      const int mrow = m0 + wrow + r * 16 + quad * 4;
#pragma unroll
      for (int i = 0; i < 4; i++) {
        if (mrow + i < M) out[(size_t)(mrow + i) * D + n] = acc[r][c][i] + bv;
      }
    }
  }
}

extern "C" void kernel_launch(void* const* d_in, const int* in_sizes, int n_in,
                              void* d_out, int out_size, void* d_ws, size_t ws_size,
                              hipStream_t stream) {
  const float* x_user   = (const float*)d_in[0];
  const float* x_item   = (const float*)d_in[1];
  const int*   ei_rates = (const int*)d_in[2];
  const int*   ei_rev   = (const int*)d_in[3];
  const int*   ei_fol   = (const int*)d_in[4];
  const float* Wl_rates = (const float*)d_in[5];
  const float* bl_rates = (const float*)d_in[6];
  const float* Wr_rates = (const float*)d_in[7];
  const float* Wl_rev   = (const float*)d_in[8];
  const float* bl_rev   = (const float*)d_in[9];
  const float* Wr_rev   = (const float*)d_in[10];
  const float* Wl_fol   = (const float*)d_in[11];
  const float* bl_fol   = (const float*)d_in[12];
  const float* Wr_fol   = (const float*)d_in[13];

  const int NU = in_sizes[0] / D;       // 50000
  const int NI = in_sizes[1] / D;       // 50000
  const int E_rates = in_sizes[2] / 2;
  const int E_rev   = in_sizes[3] / 2;
  const int E_fol   = in_sizes[4] / 2;
  const int nbkt = ((NU > NI ? NU : NI) + 127) / 128;   // 391

  // ---- workspace carve-up (byte-based, 16B aligned) ----
  char* wsb = (char*)d_ws;
  size_t off = 0;
  auto take = [&](size_t bytes) {
    char* p = wsb + off;
    off += (bytes + 15) & ~(size_t)15;
    return p;
  };
  int* bhist = (int*)take(3 * NBB * 4);          // zeroed
  const size_t zero_bytes = off;
  int* bbase = (int*)take(3 * NBB * 4);
  int* bcur  = (int*)take(3 * NBB * 4);
  unsigned* part_rates = (unsigned*)take((size_t)E_rates * 4);
  unsigned* part_rev   = (unsigned*)take((size_t)E_rev * 4);
  unsigned* part_fol   = (unsigned*)take((size_t)E_fol * 4);
  int* es_rates = (int*)take((size_t)E_rates * 4);
  int* es_rev   = (int*)take((size_t)E_rev * 4);
  int* es_fol   = (int*)take((size_t)E_fol * 4);
  int* rp_rates = (int*)take((size_t)(NI + 1) * 4);
  int* rp_rev   = (int*)take((size_t)(NU + 1) * 4);
  int* rp_fol   = (int*)take((size_t)(NU + 1) * 4);
  unsigned short* xb_user    = (unsigned short*)take((size_t)NU * D * 2);
  unsigned short* xb_item    = (unsigned short*)take((size_t)NI * D * 2);
  unsigned short* mean_rates = (unsigned short*)take((size_t)NI * D * 2);
  unsigned short* mean_rev   = (unsigned short*)take((size_t)NU * D * 2);
  unsigned short* mean_fol   = (unsigned short*)take((size_t)NU * D * 2);
  unsigned short* Wb_user    = (unsigned short*)take(128 * 384 * 2);
  unsigned short* Wb_item    = (unsigned short*)take(128 * 256 * 2);
  float* b_user = (float*)take(128 * 4);
  float* b_item = (float*)take(128 * 4);

  hipMemsetAsync(d_ws, 0, zero_bytes, stream);
  prep_kernel<<<128, 384, 0, stream>>>(Wl_rates, Wr_rates, bl_rates,
                                       Wl_rev, Wr_rev, bl_rev,
                                       Wl_fol, Wr_fol, bl_fol,
                                       Wb_user, Wb_item, b_user, b_item);
  {
    int n4u = NU * D / 4, n4i = NI * D / 4;
    conv2_kernel<<<(n4u + n4i + 255) / 256, 256, 0, stream>>>(
        x_user, x_item, xb_user, xb_item, n4u, n4i);
  }

  Rel3 R;
  R.ei[0] = ei_rates; R.ne[0] = E_rates; R.nb[0] = (E_rates + 2047) / 2048;
  R.ei[1] = ei_rev;   R.ne[1] = E_rev;   R.nb[1] = (E_rev + 2047) / 2048;
  R.ei[2] = ei_fol;   R.ne[2] = E_fol;   R.nb[2] = (E_fol + 2047) / 2048;
  bhist_kernel<<<R.nb[0] + R.nb[1] + R.nb[2], 256, 0, stream>>>(R, bhist);

  scanb_kernel<<<1, 192, 0, stream>>>(bhist, bbase, bcur, nbkt);

  PArgs P;
  P.ei[0] = ei_rates; P.ne[0] = E_rates; P.nb[0] = (E_rates + 4095) / 4096; P.part[0] = part_rates;
  P.ei[1] = ei_rev;   P.ne[1] = E_rev;   P.nb[1] = (E_rev + 4095) / 4096;   P.part[1] = part_rev;
  P.ei[2] = ei_fol;   P.ne[2] = E_fol;   P.nb[2] = (E_fol + 4095) / 4096;   P.part[2] = part_fol;
  part_kernel<<<P.nb[0] + P.nb[1] + P.nb[2], 256, 0, stream>>>(P, bcur, nbkt);

  S2Args S2;
  S2.part[0] = part_rates; S2.rp[0] = rp_rates; S2.es[0] = es_rates; S2.m[0] = NI;
  S2.part[1] = part_rev;   S2.rp[1] = rp_rev;   S2.es[1] = es_rev;   S2.m[1] = NU;
  S2.part[2] = part_fol;   S2.rp[2] = rp_fol;   S2.es[2] = es_fol;   S2.m[2] = NU;
  sort2_kernel<<<3 * nbkt, 256, 0, stream>>>(S2, bbase, nbkt);

  GatherArgs ga;
  ga.xb[0] = xb_user; ga.rp[0] = rp_rates; ga.es[0] = es_rates; ga.mean[0] = mean_rates;
  ga.m[0] = NI; ga.nb[0] = (NI + 3) / 4;
  ga.xb[1] = xb_item; ga.rp[1] = rp_rev;   ga.es[1] = es_rev;   ga.mean[1] = mean_rev;
  ga.m[1] = NU; ga.nb[1] = (NU + 3) / 4;
  ga.xb[2] = xb_user; ga.rp[2] = rp_fol;   ga.es[2] = es_fol;   ga.mean[2] = mean_fol;
  ga.m[2] = NU; ga.nb[2] = (NU + 3) / 4;
  gather3_kernel<<<ga.nb[0] + ga.nb[1] + ga.nb[2], 256, 0, stream>>>(ga);

  GemmArgs gma;
  gma.su.s[0] = mean_rev;   gma.su.s[1] = mean_fol; gma.su.s[2] = xb_user;
  gma.si.s[0] = mean_rates; gma.si.s[1] = xb_item;  gma.si.s[2] = nullptr;
  gma.wbU = Wb_user; gma.wbI = Wb_item;
  gma.bU = b_user;   gma.bI = b_item;
  gma.outU = (float*)d_out;
  gma.outI = (float*)d_out + (size_t)NU * D;
  gma.MU = NU; gma.MI = NI;
  gma.nbU = (NU + 63) / 64;
  const int nbI = (NI + 63) / 64;
  gemm2_kernel<<<gma.nbU + nbI, 256, 0, stream>>>(gma);
}